// Round 5
// baseline (746.996 us; speedup 1.0000x reference)
//
#include <hip/hip_runtime.h>
#include <cstdint>
#include <cstddef>

// Problem constants (static shapes from the reference)
#define CDIM  1024      // C
#define DTDIM 1024      // D*T
#define MDIM  65536     // B * D * T
#define BDIM  64        // B (batch / sentences)
#define VNUM  50        // valid_num

typedef __attribute__((ext_vector_type(8))) short bf16x8;
typedef __attribute__((ext_vector_type(4))) float f32x4;

__device__ __forceinline__ float bf2f(unsigned int u16) {
  return __uint_as_float(u16 << 16);
}
__device__ __forceinline__ unsigned short f2bf(float x) {
  unsigned int u = __float_as_uint(x);
  u += 0x7fffu + ((u >> 16) & 1u);   // round-to-nearest-even
  return (unsigned short)(u >> 16);
}

// async global -> LDS, 16B per lane; LDS dest is wave-uniform base + lane*16
__device__ __forceinline__ void gload16(const void* g, void* l) {
  __builtin_amdgcn_global_load_lds((const __attribute__((address_space(1))) void*)g,
                                   (__attribute__((address_space(3))) void*)l,
                                   16, 0, 0);
}

// ---------------------------------------------------------------------------
// 1) videos fp32 [b][c][dt] -> At bf16 [b*1024+dt][c]  (64x64 LDS transpose)
//    float4 loads, packed 2xbf16 stores, per-(ctile,b,dt) partial sums (no atomics)
// grid (16 dt-tiles, 16 c-tiles, 64 b), 256 thr
__global__ void k_transpose_videos(const float* __restrict__ vid,
                                   unsigned short* __restrict__ At,
                                   float* __restrict__ vpart) {
  __shared__ float t[64][65];
  const int tid = threadIdx.x;
  const int dt0 = blockIdx.x * 64, c0 = blockIdx.y * 64, b = blockIdx.z;
  const int lc = tid >> 4;          // 0..15 (c-row within pass)
  const int l4 = (tid & 15) * 4;    // dt offset (float4)
  const float* src = vid + ((size_t)b * CDIM + c0) * DTDIM + dt0;
#pragma unroll
  for (int p = 0; p < 4; p++) {
    const int c = p * 16 + lc;
    const float4 f = *reinterpret_cast<const float4*>(&src[(size_t)c * DTDIM + l4]);
    t[c][l4 + 0] = f.x; t[c][l4 + 1] = f.y; t[c][l4 + 2] = f.z; t[c][l4 + 3] = f.w;
  }
  __syncthreads();
  const int dr = tid >> 5;          // 0..7 (dt-row within pass)
  const int cl = tid & 31;          // c-pair index
  unsigned int* dstbase = reinterpret_cast<unsigned int*>(
      At + ((size_t)(b * DTDIM + dt0)) * CDIM + c0);
#pragma unroll
  for (int p = 0; p < 8; p++) {
    const int dt = p * 8 + dr;
    const float a0 = t[2 * cl][dt], a1 = t[2 * cl + 1][dt];
    const unsigned int u = (unsigned int)f2bf(a0) | ((unsigned int)f2bf(a1) << 16);
    dstbase[(size_t)dt * 512 + cl] = u;
    float s = a0 + a1;
    s += __shfl_xor(s, 1);  s += __shfl_xor(s, 2);  s += __shfl_xor(s, 4);
    s += __shfl_xor(s, 8);  s += __shfl_xor(s, 16);
    if (cl == 0)
      vpart[(size_t)blockIdx.y * MDIM + (size_t)b * DTDIM + dt0 + dt] = s;
  }
}

// 1b) reduce the 16 c-tile partials -> vsums
// grid (256), 256 thr
__global__ void k_vsum_reduce(const float* __restrict__ vpart,
                              float* __restrict__ vsums) {
  const int i = blockIdx.x * 256 + threadIdx.x;
  float s = 0.f;
#pragma unroll
  for (int ct = 0; ct < 16; ct++) s += vpart[(size_t)ct * MDIM + i];
  vsums[i] = s;
}

// ---------------------------------------------------------------------------
// 2) W_v fp32 [kb][c][f] -> Wt bf16 [kb*256+f][c]
// grid (8 f-tiles, 32 c-tiles, 4 kb), 256 thr
__global__ void k_transpose_W(const float* __restrict__ W,
                              unsigned short* __restrict__ Wt) {
  __shared__ float t[32][33];
  const int tx = threadIdx.x & 31, ty = threadIdx.x >> 5;
  const int f0 = blockIdx.x * 32, c0 = blockIdx.y * 32, kb = blockIdx.z;
  const float* src = W + ((size_t)kb * CDIM + c0) * 256 + f0;
#pragma unroll
  for (int i = 0; i < 4; i++) {
    const int cl = ty + i * 8;
    t[cl][tx] = src[(size_t)cl * 256 + tx];
  }
  __syncthreads();
  unsigned short* dst = Wt + ((size_t)(kb * 256 + f0)) * CDIM + c0;
#pragma unroll
  for (int i = 0; i < 4; i++) {
    const int fl = ty + i * 8;
    dst[(size_t)fl * CDIM + tx] = f2bf(t[tx][fl]);
  }
}

// ---------------------------------------------------------------------------
// 3) per-row fp32 sums of a bf16 [nrows][1024] matrix (one wave per row)
__global__ void k_row_sums(const unsigned short* __restrict__ A,
                           float* __restrict__ out, int nrows) {
  const int wave = threadIdx.x >> 6, lane = threadIdx.x & 63;
  const int row = blockIdx.x * 4 + wave;
  if (row >= nrows) return;
  const unsigned short* r = A + (size_t)row * 1024;
  float s = 0.f;
#pragma unroll
  for (int h = 0; h < 2; h++) {
    const uint4 u = *reinterpret_cast<const uint4*>(r + h * 512 + lane * 8);
    s += bf2f(u.x & 0xffffu) + bf2f(u.x >> 16);
    s += bf2f(u.y & 0xffffu) + bf2f(u.y >> 16);
    s += bf2f(u.z & 0xffffu) + bf2f(u.z >> 16);
    s += bf2f(u.w & 0xffffu) + bf2f(u.w >> 16);
  }
#pragma unroll
  for (int o = 32; o; o >>= 1) s += __shfl_down(s, o);
  if (lane == 0) out[row] = s;
}

// ---------------------------------------------------------------------------
// 4) sentence projection — latency-parallel: 1024 thr, c split 4-ways
// grid (64 s, 4 j), 1024 thr
__global__ void k_scat(const float* __restrict__ sent, const float* __restrict__ Ws,
                       const float* __restrict__ bs, unsigned short* __restrict__ scat,
                       float* __restrict__ snorm2) {
  const int s = blockIdx.x, j = blockIdx.y, tid = threadIdx.x;
  __shared__ float sc[1024];
  __shared__ float red[16];
  __shared__ float part[4][256];
  const float x = sent[(size_t)s * 1024 + tid];
  sc[tid] = x;
  float p = x;
#pragma unroll
  for (int o = 32; o; o >>= 1) p += __shfl_down(p, o);
  if ((tid & 63) == 0) red[tid >> 6] = p;
  __syncthreads();
  float mean = 0.f;
#pragma unroll
  for (int w = 0; w < 16; w++) mean += red[w];
  mean *= (1.f / 1024.f);
  const int f = tid & 255, cq = tid >> 8;
  const float* W = Ws + ((size_t)(j * 1024 + cq * 256)) * 256 + f;
  float acc = 0.f;
#pragma unroll 8
  for (int c = 0; c < 256; c++)
    acc += (sc[cq * 256 + c] - mean) * W[(size_t)c * 256];
  part[cq][f] = acc;
  __syncthreads();
  if (tid < 256) {
    const int n = j * 256 + tid;
    const float val = part[0][tid] + part[1][tid] + part[2][tid] + part[3][tid] + bs[n];
    scat[(size_t)s * 1024 + n] = f2bf(val);
    float v2 = val * val;
#pragma unroll
    for (int o = 32; o; o >>= 1) v2 += __shfl_down(v2, o);
    if ((tid & 63) == 0) atomicAdd(&snorm2[s], v2);
  }
}

// ---------------------------------------------------------------------------
// 5) FUSED GEMM — A-read-once + conflict-free swizzle + 3-DEEP A PREFETCH:
//    A(kt) comes from HBM (At streamed once, never cache-hot); with 2-deep
//    staging it was issued only ONE phase (~500cyc) before use -> every kt
//    exposed ~400cyc of HBM latency (R4: 3750cyc/kt vs ~500 compute floor,
//    1 block/CU so nothing hides it). sA is now 3 buffers; A staged TWO
//    K-tiles ahead (2 phases > HBM ~900cyc). B (L2-hot Wt) stays 2-deep.
//    Exact vmcnt counts: waves 0-3 steady=10 (leave [A(k+1),B(k+1)x8,A(k+2)]),
//    edges kt==0/kt==30 =9; waves 4-7 always 8.
// LDS: sA 3x4KB | sB 2x64KB | stile 16KB | invSn 256B | vn 2KB | invVn 256B
//      = 162304 B; vtile [64][1024] bf16 = 128KB overlays sA+sB post-K-loop.
// grid (1024), 512 thr
__global__ __launch_bounds__(512, 2) void k_gemm_fused(
    const unsigned short* __restrict__ At, const unsigned short* __restrict__ Wt,
    const float* __restrict__ vsums, const float* __restrict__ csW,
    const float* __restrict__ bv, const unsigned short* __restrict__ scat,
    const float* __restrict__ snorm2, const int* __restrict__ mask,
    float* __restrict__ sim, float* __restrict__ pm) {
  __shared__ alignas(16) char smem[162304];
  unsigned short* sA    = (unsigned short*)smem;              // 3 x [64][32]
  unsigned short* sB    = (unsigned short*)(smem + 12288);    // 2 x [1024][32]
  unsigned short* stile = (unsigned short*)(smem + 143360);   // [64][128]
  float* invSnLds       = (float*)(smem + 159744);            // 64
  float* vnLds          = (float*)(smem + 160000);            // 8 x 64
  float* invVnLds       = (float*)(smem + 162048);            // 64
  unsigned short* vtile = (unsigned short*)smem;              // [64][1024] overlay

  const int tid = threadIdx.x;
  const int wave = tid >> 6, lane = tid & 63;
  const int quad = lane >> 4, l16 = lane & 15;
  const int m0 = blockIdx.x * 64;
  const int ng = wave;                         // each wave owns one 128-c n-strip
  const int r4 = lane >> 2, c4 = lane & 3;     // staging decomposition

  if (tid < 64) invSnLds[tid] = 1.f / fmaxf(sqrtf(snorm2[tid]), 1e-8f);

  f32x4 acc[4][8];
#pragma unroll
  for (int i = 0; i < 4; i++)
#pragma unroll
    for (int j = 0; j < 8; j++) acc[i][j] = f32x4{0.f, 0.f, 0.f, 0.f};

  // stage B K-tile (all 8 waves, 8 instrs each); source pre-swizzled (row>>1)&3
  auto stage_b = [&](int buf, int kt) {
    const int koff = kt * 32;
    unsigned short* dB = sB + buf * 32768;
    const int gsw = (c4 ^ ((r4 >> 1) & 3)) * 8;
#pragma unroll
    for (int ii = 0; ii < 8; ii++) {
      const int qq = wave * 8 + ii;
      const int r = qq * 16 + r4;            // n row 0..1023
      gload16(Wt + (size_t)r * CDIM + koff + gsw, dB + qq * 512);
    }
  };
  // stage A K-tile (waves 0-3, 1 instr each)
  auto stage_a = [&](int buf, int kt) {
    if (wave < 4) {
      const int koff = kt * 32;
      const int gsw = (c4 ^ ((r4 >> 1) & 3)) * 8;
      const int r = wave * 16 + r4;          // m row 0..63
      gload16(At + (size_t)(m0 + r) * CDIM + koff + gsw,
              sA + buf * 2048 + wave * 512);
    }
  };

  auto stage_stile = [&](int cc) {
#pragma unroll
    for (int ii = 0; ii < 2; ii++) {
      const int q = ii * 8 + wave;           // 0..15
      const int srow = q * 4 + (lane >> 4);  // 0..63
      const int g = (lane & 15) ^ (srow & 15);
      gload16(scat + (size_t)srow * 1024 + cc * 128 + g * 8, stile + q * 512);
    }
  };

  auto compute = [&](int abuf, int bbuf) {
    const unsigned short* bA = sA + abuf * 2048;
    const unsigned short* bB = sB + bbuf * 32768;
    const int p8 = (quad ^ ((l16 >> 1) & 3)) * 8;   // conflict-free chunk
    bf16x8 aF[4];
#pragma unroll
    for (int i = 0; i < 4; i++)
      aF[i] = *reinterpret_cast<const bf16x8*>(&bA[(i * 16 + l16) * 32 + p8]);
    __builtin_amdgcn_s_setprio(1);
#pragma unroll
    for (int jb = 0; jb < 2; jb++) {
      bf16x8 bF[4];
#pragma unroll
      for (int jj = 0; jj < 4; jj++)
        bF[jj] = *reinterpret_cast<const bf16x8*>(
            &bB[(ng * 128 + (jb * 4 + jj) * 16 + l16) * 32 + p8]);
#pragma unroll
      for (int i = 0; i < 4; i++)
#pragma unroll
        for (int jj = 0; jj < 4; jj++)
          acc[i][jb * 4 + jj] = __builtin_amdgcn_mfma_f32_16x16x32_bf16(
              aF[i], bF[jj], acc[i][jb * 4 + jj], 0, 0, 0);
    }
    __builtin_amdgcn_s_setprio(0);
    // no DS op may be pending when this wave signals the next barrier
    // (buf is re-staged one barrier later). Drain lgkm; pin with sched_barrier.
    asm volatile("s_waitcnt lgkmcnt(0)" ::: "memory");
    __builtin_amdgcn_sched_barrier(0);
  };

  // ---- K-loop: 32 steps; A 3-deep (staged kt+2), B 2-deep, counted vmcnt ----
  stage_a(0, 0);                             // A0 -> buf 0
  stage_a(1, 1);                             // A1 -> buf 1
  stage_b(0, 0);                             // B0
  int bcur = 0;
#pragma unroll 1
  for (int kt = 0; kt < 31; ++kt) {
    stage_b(bcur ^ 1, kt + 1);               // B(kt+1): stays in flight
    if (kt < 30) stage_a((kt + 2) % 3, kt + 2);  // A(kt+2): 2 phases ahead
    if (wave < 4) {
      if (kt == 0 || kt == 30) asm volatile("s_waitcnt vmcnt(9)" ::: "memory");
      else                     asm volatile("s_waitcnt vmcnt(10)" ::: "memory");
    } else {
      asm volatile("s_waitcnt vmcnt(8)" ::: "memory");
    }
    __builtin_amdgcn_s_barrier();            // all waves' parts landed
    asm volatile("" ::: "memory");
    compute(kt % 3, bcur);
    __builtin_amdgcn_s_barrier();            // reads done -> bufs re-stageable
    bcur ^= 1;
  }
  stage_stile(0);                            // rides with tail drain
  asm volatile("s_waitcnt vmcnt(0)" ::: "memory");
  __builtin_amdgcn_s_barrier();
  asm volatile("" ::: "memory");
  compute(31 % 3, bcur);
  __syncthreads();                           // staging dead; vtile overlay begins

  // ---- epilogue: centering+bias -> bf16 vtile (swizzled), ss accumulate ----
  const float inv1024 = 1.f / 1024.f;
  float ss[4][4];
#pragma unroll
  for (int i = 0; i < 4; i++)
#pragma unroll
    for (int rr = 0; rr < 4; rr++) ss[i][rr] = 0.f;
#pragma unroll
  for (int i = 0; i < 4; i++) {
    const int rbase = i * 16 + quad * 4;
    const float4 vs = *reinterpret_cast<const float4*>(&vsums[m0 + rbase]);
    const float mu[4] = {vs.x * inv1024, vs.y * inv1024, vs.z * inv1024, vs.w * inv1024};
#pragma unroll
    for (int j = 0; j < 8; j++) {
      const int c = ng * 128 + j * 16 + l16;
      const float cs = csW[c];
      const float bb = bv[c];
#pragma unroll
      for (int rr = 0; rr < 4; rr++) {
        const int m = rbase + rr;
        const float val = acc[i][j][rr] - mu[rr] * cs + bb;
        ss[i][rr] += val * val;
        vtile[m * 1024 + (((c >> 3) ^ (m & 15)) * 8) + (c & 7)] = f2bf(val);
      }
    }
  }

  // row norms: reduce over 16 l16 lanes (this wave's 128 c), publish per wave
#pragma unroll
  for (int i = 0; i < 4; i++)
#pragma unroll
    for (int rr = 0; rr < 4; rr++) {
      float v = ss[i][rr];
      v += __shfl_xor(v, 1); v += __shfl_xor(v, 2);
      v += __shfl_xor(v, 4); v += __shfl_xor(v, 8);
      if (l16 == 0) vnLds[ng * 64 + i * 16 + quad * 4 + rr] = v;
    }
  __syncthreads();
  if (tid < 64) {
    float nv = 0.f;
#pragma unroll
    for (int w = 0; w < 8; w++) nv += vnLds[w * 64 + tid];
    invVnLds[tid] = 1.f / fmaxf(sqrtf(nv), 1e-8f);
  }

  // ---- MFMA2: P[s=64][m=64] += scat . vtile^T, 8 chunks of 128 c ----
  const int sgrp = wave >> 2, mgrp = wave & 3;  // 2 s-groups x 4 m-groups
  f32x4 acc2[2];
#pragma unroll
  for (int i2 = 0; i2 < 2; i2++) acc2[i2] = f32x4{0.f, 0.f, 0.f, 0.f};
#pragma unroll 1
  for (int cc = 0; cc < 8; cc++) {
    if (cc > 0) {
      __syncthreads();                       // prior chunk readers done (full drain)
      stage_stile(cc);
      asm volatile("s_waitcnt vmcnt(0)" ::: "memory");
    }
    __syncthreads();                         // all parts landed (cc=0: vtile ready)
#pragma unroll
    for (int ks2 = 0; ks2 < 4; ks2++) {
      const int sl2 = ((ks2 * 4 + quad) ^ l16) * 8;
      bf16x8 a2[2], b2;
#pragma unroll
      for (int i2 = 0; i2 < 2; i2++)
        a2[i2] = *reinterpret_cast<const bf16x8*>(
            &stile[(sgrp * 32 + i2 * 16 + l16) * 128 + sl2]);
      b2 = *reinterpret_cast<const bf16x8*>(
          &vtile[(mgrp * 16 + l16) * 1024 + cc * 128 + sl2]);
#pragma unroll
      for (int i2 = 0; i2 < 2; i2++)
        acc2[i2] = __builtin_amdgcn_mfma_f32_16x16x32_bf16(a2[i2], b2, acc2[i2], 0, 0, 0);
    }
  }

  // ---- normalize + mask + write sim (and positive_map) ----
  const int b0 = m0 >> 10;
  const int m = mgrp * 16 + l16;
  const float invVn = invVnLds[m];
  const int mk = mask[m0 + m];
#pragma unroll
  for (int i2 = 0; i2 < 2; i2++) {
#pragma unroll
    for (int reg = 0; reg < 4; reg++) {
      const int s = sgrp * 32 + i2 * 16 + quad * 4 + reg;
      float val = acc2[i2][reg] * invVn * invSnLds[s];
      if (mk == 0) val = -__builtin_inff();
      sim[(size_t)s * MDIM + m0 + m] = val;
      if (s == b0) pm[m0 + m] = val;
    }
  }
}

// ---------------------------------------------------------------------------
// 7) per-(s,b): top-50, IoU penalty, score — ONE WAVE per (s,b), zero barriers
// grid (1024), 256 thr (4 waves)
__global__ void k_topk(const float* __restrict__ sim, const float* __restrict__ iou,
                       const float* __restrict__ lam, float* __restrict__ scores) {
  const int wave = threadIdx.x >> 6, lane = threadIdx.x & 63;
  const int sb = blockIdx.x * 4 + wave;
  const int s = sb >> 6, b = sb & 63;
  __shared__ float tvs[4][VNUM];
  __shared__ int tis[4][VNUM];

  const float* row = sim + (size_t)s * MDIM + (size_t)b * 1024;
  float v[16];
#pragma unroll
  for (int j = 0; j < 16; j++) v[j] = row[j * 64 + lane];

  for (int k = 0; k < VNUM; k++) {
    float bv = v[0]; int bj = 0;
#pragma unroll
    for (int j = 1; j < 16; j++)
      if (v[j] > bv) { bv = v[j]; bj = j; }
    int bidx = bj * 64 + lane;
#pragma unroll
    for (int o = 1; o < 64; o <<= 1) {
      const float ov = __shfl_xor(bv, o);
      const int oi = __shfl_xor(bidx, o);
      if (ov > bv || (ov == bv && oi < bidx)) { bv = ov; bidx = oi; }
    }
    if (lane == 0) { tvs[wave][k] = bv; tis[wave][k] = bidx; }
    const int wj = bidx >> 6;
    const bool mine = (bidx & 63) == lane;
#pragma unroll
    for (int j = 0; j < 16; j++)
      if (mine && wj == j) v[j] = -__builtin_inff();
  }
  __syncthreads();

  float contrib = 0.f;
  if (lane < VNUM) {
    const int myidx = tis[wave][lane];
    float pen = 0.f;
    for (int l = lane + 1; l < VNUM; l++) {
      const float u = iou[(size_t)tis[wave][l] * 1024 + myidx];
      pen += u * u;
    }
    contrib = tvs[wave][lane] * expf(-pen / lam[0]);
  }
#pragma unroll
  for (int o = 32; o; o >>= 1) contrib += __shfl_down(contrib, o);
  if (lane == 0) scores[s * 64 + b] = contrib * (1.f / VNUM);
}

// ---------------------------------------------------------------------------
// 8) final 64x64 loss reduction
__global__ void k_loss(const float* __restrict__ scores, float* __restrict__ out) {
  __shared__ float S[64 * 64];
  __shared__ float diag[64];
  __shared__ float rmax[64], cmax[64];
  const int tid = threadIdx.x;
#pragma unroll
  for (int q = 0; q < 16; q++) S[tid + q * 256] = scores[tid + q * 256];
  __syncthreads();
  if (tid < 64) diag[tid] = S[tid * 64 + tid];
  __syncthreads();
  if (tid < 64) {
    float rm = 0.f, cm = 0.f;
    for (int x = 0; x < 64; x++) {
      if (x != tid) {
        const float cs = 0.2f + S[tid * 64 + x] - diag[tid];
        rm = fmaxf(rm, fmaxf(cs, 0.f));
        const float ci = 0.2f + S[x * 64 + tid] - diag[tid];
        cm = fmaxf(cm, fmaxf(ci, 0.f));
      }
    }
    rmax[tid] = rm; cmax[tid] = cm;
  }
  __syncthreads();
  if (tid == 0) {
    float L = 0.f;
    for (int t = 0; t < 64; t++) L += rmax[t] + cmax[t];
    out[0] = L * (1.f / 64.f);
  }
}

// ---------------------------------------------------------------------------
extern "C" void kernel_launch(void* const* d_in, const int* in_sizes, int n_in,
                              void* d_out, int out_size, void* d_ws, size_t ws_size,
                              hipStream_t stream) {
  (void)in_sizes; (void)n_in; (void)out_size; (void)ws_size;
  const float* videos = (const float*)d_in[0];
  const float* sent   = (const float*)d_in[1];
  const float* lam    = (const float*)d_in[2];
  const int*   mask   = (const int*)d_in[3];
  const float* iou    = (const float*)d_in[4];
  const float* W_v    = (const float*)d_in[6];
  const float* b_v    = (const float*)d_in[7];
  const float* W_s    = (const float*)d_in[8];
  const float* b_s    = (const float*)d_in[9];
  float* out = (float*)d_out;

  char* ws = (char*)d_ws;
  unsigned short* At   = (unsigned short*)(ws + 0);           // 128 MB
  float* sim           = (float*)(ws + 134217728);            // 16 MB
  float* vpart         = (float*)(ws + 134217728);            // 4 MB, aliases sim
                                                              // (consumed before gemm writes sim)
  unsigned short* Wt   = (unsigned short*)(ws + 150994944);   // 2 MB
  unsigned short* scat = (unsigned short*)(ws + 153092096);   // 128 KB
  float* vsums         = (float*)(ws + 153223168);            // 256 KB
  float* snorm2        = (float*)(ws + 153485312);            // 256 B
  float* csW           = (float*)(ws + 153485568);            // 4 KB
  float* scores        = (float*)(ws + 153489664);            // 16 KB

  // zero snorm2 only (vsums computed by plain stores + reduce)
  hipMemsetAsync(snorm2, 0, 256, stream);

  k_transpose_videos<<<dim3(16, 16, 64), 256, 0, stream>>>(videos, At, vpart);
  k_vsum_reduce<<<256, 256, 0, stream>>>(vpart, vsums);
  k_transpose_W<<<dim3(8, 32, 4), 256, 0, stream>>>(W_v, Wt);
  k_row_sums<<<256, 256, 0, stream>>>(Wt, csW, 1024);
  k_scat<<<dim3(64, 4), 1024, 0, stream>>>(sent, W_s, b_s, scat, snorm2);
  k_gemm_fused<<<dim3(1024), 512, 0, stream>>>(At, Wt, vsums, csW, b_v, scat,
                                               snorm2, mask, sim, out + 1);
  k_topk<<<dim3(1024), 256, 0, stream>>>(sim, iou, lam, scores);
  k_loss<<<1, 256, 0, stream>>>(scores, out);
}

// Round 6
// 724.876 us; speedup vs baseline: 1.0305x; 1.0305x over previous
//
#include <hip/hip_runtime.h>
#include <cstdint>
#include <cstddef>

// Problem constants (static shapes from the reference)
#define CDIM  1024      // C
#define DTDIM 1024      // D*T
#define MDIM  65536     // B * D * T
#define BDIM  64        // B (batch / sentences)
#define VNUM  50        // valid_num

typedef __attribute__((ext_vector_type(8))) short bf16x8;
typedef __attribute__((ext_vector_type(4))) float f32x4;

__device__ __forceinline__ float bf2f(unsigned int u16) {
  return __uint_as_float(u16 << 16);
}
__device__ __forceinline__ unsigned short f2bf(float x) {
  unsigned int u = __float_as_uint(x);
  u += 0x7fffu + ((u >> 16) & 1u);   // round-to-nearest-even
  return (unsigned short)(u >> 16);
}

// async global -> LDS, 16B per lane; LDS dest is wave-uniform base + lane*16
__device__ __forceinline__ void gload16(const void* g, void* l) {
  __builtin_amdgcn_global_load_lds((const __attribute__((address_space(1))) void*)g,
                                   (__attribute__((address_space(3))) void*)l,
                                   16, 0, 0);
}

// ---------------------------------------------------------------------------
// 1) videos fp32 [b][c][dt] -> At bf16 [b*1024+dt][c]  (64x64 LDS transpose)
// grid (16 dt-tiles, 16 c-tiles, 64 b), 256 thr
__global__ void k_transpose_videos(const float* __restrict__ vid,
                                   unsigned short* __restrict__ At,
                                   float* __restrict__ vpart) {
  __shared__ float t[64][65];
  const int tid = threadIdx.x;
  const int dt0 = blockIdx.x * 64, c0 = blockIdx.y * 64, b = blockIdx.z;
  const int lc = tid >> 4;          // 0..15 (c-row within pass)
  const int l4 = (tid & 15) * 4;    // dt offset (float4)
  const float* src = vid + ((size_t)b * CDIM + c0) * DTDIM + dt0;
#pragma unroll
  for (int p = 0; p < 4; p++) {
    const int c = p * 16 + lc;
    const float4 f = *reinterpret_cast<const float4*>(&src[(size_t)c * DTDIM + l4]);
    t[c][l4 + 0] = f.x; t[c][l4 + 1] = f.y; t[c][l4 + 2] = f.z; t[c][l4 + 3] = f.w;
  }
  __syncthreads();
  const int dr = tid >> 5;          // 0..7 (dt-row within pass)
  const int cl = tid & 31;          // c-pair index
  unsigned int* dstbase = reinterpret_cast<unsigned int*>(
      At + ((size_t)(b * DTDIM + dt0)) * CDIM + c0);
#pragma unroll
  for (int p = 0; p < 8; p++) {
    const int dt = p * 8 + dr;
    const float a0 = t[2 * cl][dt], a1 = t[2 * cl + 1][dt];
    const unsigned int u = (unsigned int)f2bf(a0) | ((unsigned int)f2bf(a1) << 16);
    dstbase[(size_t)dt * 512 + cl] = u;
    float s = a0 + a1;
    s += __shfl_xor(s, 1);  s += __shfl_xor(s, 2);  s += __shfl_xor(s, 4);
    s += __shfl_xor(s, 8);  s += __shfl_xor(s, 16);
    if (cl == 0)
      vpart[(size_t)blockIdx.y * MDIM + (size_t)b * DTDIM + dt0 + dt] = s;
  }
}

// 1b) reduce the 16 c-tile partials -> vsums
// grid (256), 256 thr
__global__ void k_vsum_reduce(const float* __restrict__ vpart,
                              float* __restrict__ vsums) {
  const int i = blockIdx.x * 256 + threadIdx.x;
  float s = 0.f;
#pragma unroll
  for (int ct = 0; ct < 16; ct++) s += vpart[(size_t)ct * MDIM + i];
  vsums[i] = s;
}

// ---------------------------------------------------------------------------
// 2) W_v fp32 [kb][c][f] -> Wt bf16 [kb*256+f][c]
// grid (8 f-tiles, 32 c-tiles, 4 kb), 256 thr
__global__ void k_transpose_W(const float* __restrict__ W,
                              unsigned short* __restrict__ Wt) {
  __shared__ float t[32][33];
  const int tx = threadIdx.x & 31, ty = threadIdx.x >> 5;
  const int f0 = blockIdx.x * 32, c0 = blockIdx.y * 32, kb = blockIdx.z;
  const float* src = W + ((size_t)kb * CDIM + c0) * 256 + f0;
#pragma unroll
  for (int i = 0; i < 4; i++) {
    const int cl = ty + i * 8;
    t[cl][tx] = src[(size_t)cl * 256 + tx];
  }
  __syncthreads();
  unsigned short* dst = Wt + ((size_t)(kb * 256 + f0)) * CDIM + c0;
#pragma unroll
  for (int i = 0; i < 4; i++) {
    const int fl = ty + i * 8;
    dst[(size_t)fl * CDIM + tx] = f2bf(t[tx][fl]);
  }
}

// ---------------------------------------------------------------------------
// 3) per-row fp32 sums of a bf16 [nrows][1024] matrix (one wave per row)
__global__ void k_row_sums(const unsigned short* __restrict__ A,
                           float* __restrict__ out, int nrows) {
  const int wave = threadIdx.x >> 6, lane = threadIdx.x & 63;
  const int row = blockIdx.x * 4 + wave;
  if (row >= nrows) return;
  const unsigned short* r = A + (size_t)row * 1024;
  float s = 0.f;
#pragma unroll
  for (int h = 0; h < 2; h++) {
    const uint4 u = *reinterpret_cast<const uint4*>(r + h * 512 + lane * 8);
    s += bf2f(u.x & 0xffffu) + bf2f(u.x >> 16);
    s += bf2f(u.y & 0xffffu) + bf2f(u.y >> 16);
    s += bf2f(u.z & 0xffffu) + bf2f(u.z >> 16);
    s += bf2f(u.w & 0xffffu) + bf2f(u.w >> 16);
  }
#pragma unroll
  for (int o = 32; o; o >>= 1) s += __shfl_down(s, o);
  if (lane == 0) out[row] = s;
}

// ---------------------------------------------------------------------------
// 4) sentence projection — latency-parallel: 1024 thr, c split 4-ways
// grid (64 s, 4 j), 1024 thr
__global__ void k_scat(const float* __restrict__ sent, const float* __restrict__ Ws,
                       const float* __restrict__ bs, unsigned short* __restrict__ scat,
                       float* __restrict__ snorm2) {
  const int s = blockIdx.x, j = blockIdx.y, tid = threadIdx.x;
  __shared__ float sc[1024];
  __shared__ float red[16];
  __shared__ float part[4][256];
  const float x = sent[(size_t)s * 1024 + tid];
  sc[tid] = x;
  float p = x;
#pragma unroll
  for (int o = 32; o; o >>= 1) p += __shfl_down(p, o);
  if ((tid & 63) == 0) red[tid >> 6] = p;
  __syncthreads();
  float mean = 0.f;
#pragma unroll
  for (int w = 0; w < 16; w++) mean += red[w];
  mean *= (1.f / 1024.f);
  const int f = tid & 255, cq = tid >> 8;
  const float* W = Ws + ((size_t)(j * 1024 + cq * 256)) * 256 + f;
  float acc = 0.f;
#pragma unroll 8
  for (int c = 0; c < 256; c++)
    acc += (sc[cq * 256 + c] - mean) * W[(size_t)c * 256];
  part[cq][f] = acc;
  __syncthreads();
  if (tid < 256) {
    const int n = j * 256 + tid;
    const float val = part[0][tid] + part[1][tid] + part[2][tid] + part[3][tid] + bs[n];
    scat[(size_t)s * 1024 + n] = f2bf(val);
    float v2 = val * val;
#pragma unroll
    for (int o = 32; o; o >>= 1) v2 += __shfl_down(v2, o);
    if ((tid & 63) == 0) atomicAdd(&snorm2[s], v2);
  }
}

// ---------------------------------------------------------------------------
// 5) PARTIAL-C FUSED GEMM — multi-block-overlap restructure:
//    BM=128 x BN=256, BK=32; 256 thr / 4 waves (2x2, wave tile 64m x 128n,
//    acc[4][8] = 128 f32). LDS 64KB, regs ~240 -> TWO INDEPENDENT blocks/CU
//    (the R2-R5 1-block/CU convoy exposed ~1300 cyc/kt of barrier/stage
//    stalls; co-resident blocks hide each other's stalls, m97-style).
//    Epilogue: centering+bias -> ss (atomicAdd vn2) and bf16 vtile chunks
//    [128][128] in LDS; MFMA2 contracts this block's 256 c into
//    P[s][m] partials via f32 atomicAdd (order-noise ~1e-7 << tolerance).
//    k_reduce then normalizes P in place into sim. Swizzles identical to
//    R4/R5 (measured SQ_LDS_BANK_CONFLICT = 0).
// LDS: sA 2x8KB @0 | sB 2x16KB @16K | stile 16KB @48K  (64KB total)
//      vtile [128][128] 32KB overlays sA+sB(buf0) after the K-loop.
// grid (2048) = 512 m-blocks x 4 n-blocks, 256 thr
__global__ __launch_bounds__(256, 2) void k_gemm_part(
    const unsigned short* __restrict__ At, const unsigned short* __restrict__ Wt,
    const float* __restrict__ vsums, const float* __restrict__ csW,
    const float* __restrict__ bv, const unsigned short* __restrict__ scat,
    float* __restrict__ P, float* __restrict__ vn2) {
  __shared__ alignas(16) char smem[65536];
  unsigned short* sA    = (unsigned short*)smem;              // 2 x [128][32]
  unsigned short* sB    = (unsigned short*)(smem + 16384);    // 2 x [256][32]
  unsigned short* stile = (unsigned short*)(smem + 49152);    // [64][128]
  unsigned short* vtile = (unsigned short*)smem;              // [128][128] overlay

  const int tid = threadIdx.x;
  const int wave = tid >> 6, lane = tid & 63;
  const int quad = lane >> 4, l16 = lane & 15;
  const int bid = blockIdx.x;
  const int m0 = (bid >> 2) * 128;          // consecutive bids share A-slab (L3)
  const int n0 = (bid & 3) * 256;
  const int wr = wave >> 1, wc = wave & 1;  // 2x2 wave grid
  const int r4 = lane >> 2, c4 = lane & 3;
  const int gsw = (c4 ^ ((r4 >> 1) & 3)) * 8;   // proven conflict-free key

  f32x4 acc[4][8];
#pragma unroll
  for (int i = 0; i < 4; i++)
#pragma unroll
    for (int j = 0; j < 8; j++) acc[i][j] = f32x4{0.f, 0.f, 0.f, 0.f};

  // stage one BK=32 K-tile: B 4 instr/wave, A 2 instr/wave -> 6 vmcnt items
  auto stage = [&](int buf, int kt) {
    const int koff = kt * 32;
    unsigned short* dB = sB + buf * 8192;
    unsigned short* dA = sA + buf * 4096;
#pragma unroll
    for (int ii = 0; ii < 4; ii++) {
      const int row = wave * 64 + ii * 16 + r4;     // 0..255
      gload16(Wt + (size_t)(n0 + row) * CDIM + koff + gsw,
              dB + (wave * 64 + ii * 16) * 32);
    }
#pragma unroll
    for (int ii = 0; ii < 2; ii++) {
      const int row = wave * 32 + ii * 16 + r4;     // 0..127
      gload16(At + (size_t)(m0 + row) * CDIM + koff + gsw,
              dA + (wave * 32 + ii * 16) * 32);
    }
  };

  auto stage_stile = [&](int cc) {                  // 4 instr/thread
#pragma unroll
    for (int ii = 0; ii < 4; ii++) {
      const int q = ii * 4 + wave;                  // 0..15
      const int srow = q * 4 + quad;                // 0..63
      const int g = l16 ^ (srow & 15);
      gload16(scat + (size_t)srow * 1024 + n0 + cc * 128 + g * 8,
              stile + q * 512);
    }
  };

  auto compute = [&](int buf) {
    const unsigned short* bA = sA + buf * 4096;
    const unsigned short* bB = sB + buf * 8192;
    const int p8 = (quad ^ ((l16 >> 1) & 3)) * 8;
    bf16x8 aF[4];
#pragma unroll
    for (int i = 0; i < 4; i++)
      aF[i] = *reinterpret_cast<const bf16x8*>(&bA[(wr * 64 + i * 16 + l16) * 32 + p8]);
    __builtin_amdgcn_s_setprio(1);
#pragma unroll
    for (int jb = 0; jb < 2; jb++) {
      bf16x8 bF[4];
#pragma unroll
      for (int jj = 0; jj < 4; jj++)
        bF[jj] = *reinterpret_cast<const bf16x8*>(
            &bB[(wc * 128 + (jb * 4 + jj) * 16 + l16) * 32 + p8]);
#pragma unroll
      for (int i = 0; i < 4; i++)
#pragma unroll
        for (int jj = 0; jj < 4; jj++)
          acc[i][jb * 4 + jj] = __builtin_amdgcn_mfma_f32_16x16x32_bf16(
              aF[i], bF[jj], acc[i][jb * 4 + jj], 0, 0, 0);
    }
    __builtin_amdgcn_s_setprio(0);
    // zero pending DS ops before signalling the next barrier (proven fence)
    asm volatile("s_waitcnt lgkmcnt(0)" ::: "memory");
    __builtin_amdgcn_sched_barrier(0);
  };

  // ---- K-loop: 32 steps, dbuf, uniform counted vmcnt(6) ----
  stage(0, 0);
  int cur = 0;
#pragma unroll 1
  for (int kt = 0; kt < 31; ++kt) {
    stage(cur ^ 1, kt + 1);                  // next tile stays in flight
    asm volatile("s_waitcnt vmcnt(6)" ::: "memory");   // current tile landed
    __builtin_amdgcn_s_barrier();
    asm volatile("" ::: "memory");
    compute(cur);
    __builtin_amdgcn_s_barrier();
    cur ^= 1;
  }
  stage_stile(0);                            // stile region disjoint from sA/sB
  asm volatile("s_waitcnt vmcnt(4)" ::: "memory");     // kt31 landed, stile flying
  __builtin_amdgcn_s_barrier();
  asm volatile("" ::: "memory");
  compute(cur);
  __syncthreads();                           // full drain: staging dead, stile landed

  // ---- epilogue: centering+bias, ss -> vn2 atomics, vals kept in regs ----
  const float inv1024 = 1.f / 1024.f;
  float vals[4][8][4];
  float ss[4][4];
#pragma unroll
  for (int i = 0; i < 4; i++)
#pragma unroll
    for (int rr = 0; rr < 4; rr++) ss[i][rr] = 0.f;
#pragma unroll
  for (int i = 0; i < 4; i++) {
    const int rbase = wr * 64 + i * 16 + quad * 4;
    const float4 vs = *reinterpret_cast<const float4*>(&vsums[m0 + rbase]);
    const float mu[4] = {vs.x * inv1024, vs.y * inv1024, vs.z * inv1024, vs.w * inv1024};
#pragma unroll
    for (int j = 0; j < 8; j++) {
      const int c = n0 + wc * 128 + j * 16 + l16;
      const float cs = csW[c];
      const float bb = bv[c];
#pragma unroll
      for (int rr = 0; rr < 4; rr++) {
        const float val = acc[i][j][rr] - mu[rr] * cs + bb;
        ss[i][rr] += val * val;
        vals[i][j][rr] = val;
      }
    }
  }
  // vn2 partials (one atomic per m per wave; 8 partials total per m)
#pragma unroll
  for (int i = 0; i < 4; i++)
#pragma unroll
    for (int rr = 0; rr < 4; rr++) {
      float v = ss[i][rr];
      v += __shfl_xor(v, 1); v += __shfl_xor(v, 2);
      v += __shfl_xor(v, 4); v += __shfl_xor(v, 8);
      if (l16 == 0)
        atomicAdd(&vn2[m0 + wr * 64 + i * 16 + quad * 4 + rr], v);
    }
  // chunk 0 (c-local 0..127, owned by wc==0 waves) -> vtile
  if (wc == 0) {
#pragma unroll
    for (int i = 0; i < 4; i++)
#pragma unroll
      for (int j = 0; j < 8; j++)
#pragma unroll
        for (int rr = 0; rr < 4; rr++) {
          const int mL = wr * 64 + i * 16 + quad * 4 + rr;
          const int cL = j * 16 + l16;
          vtile[mL * 128 + (((cL >> 3) ^ (mL & 15)) * 8) + (cL & 7)] =
              f2bf(vals[i][j][rr]);
        }
  }
  __syncthreads();

  // ---- MFMA2: P[s=64][m=128] += scat . vcat^T, 2 chunks of 128 c ----
  f32x4 acc2[4][2];
#pragma unroll
  for (int i2 = 0; i2 < 4; i2++)
#pragma unroll
    for (int j2 = 0; j2 < 2; j2++) acc2[i2][j2] = f32x4{0.f, 0.f, 0.f, 0.f};

#pragma unroll
  for (int cc = 0; cc < 2; cc++) {
    if (cc == 1) {
      __syncthreads();                       // chunk0 reads done (lgkm drained)
      if (wc == 1) {
#pragma unroll
        for (int i = 0; i < 4; i++)
#pragma unroll
          for (int j = 0; j < 8; j++)
#pragma unroll
            for (int rr = 0; rr < 4; rr++) {
              const int mL = wr * 64 + i * 16 + quad * 4 + rr;
              const int cL = j * 16 + l16;
              vtile[mL * 128 + (((cL >> 3) ^ (mL & 15)) * 8) + (cL & 7)] =
                  f2bf(vals[i][j][rr]);
            }
      }
      stage_stile(1);
      asm volatile("s_waitcnt vmcnt(0)" ::: "memory");
      __syncthreads();
    }
#pragma unroll
    for (int ks2 = 0; ks2 < 4; ks2++) {
      const int sl2 = ((ks2 * 4 + quad) ^ l16) * 8;
      bf16x8 a2[4], b2[2];
#pragma unroll
      for (int i2 = 0; i2 < 4; i2++)
        a2[i2] = *reinterpret_cast<const bf16x8*>(&stile[(i2 * 16 + l16) * 128 + sl2]);
#pragma unroll
      for (int j2 = 0; j2 < 2; j2++)
        b2[j2] = *reinterpret_cast<const bf16x8*>(
            &vtile[(wave * 32 + j2 * 16 + l16) * 128 + sl2]);
#pragma unroll
      for (int i2 = 0; i2 < 4; i2++)
#pragma unroll
        for (int j2 = 0; j2 < 2; j2++)
          acc2[i2][j2] = __builtin_amdgcn_mfma_f32_16x16x32_bf16(
              a2[i2], b2[j2], acc2[i2][j2], 0, 0, 0);
    }
  }

  // ---- P partial write (f32 atomics; 4 n-blocks accumulate per (s,m)) ----
#pragma unroll
  for (int i2 = 0; i2 < 4; i2++)
#pragma unroll
    for (int j2 = 0; j2 < 2; j2++)
#pragma unroll
      for (int reg = 0; reg < 4; reg++) {
        const int s = i2 * 16 + quad * 4 + reg;
        const int mL = wave * 32 + j2 * 16 + l16;
        atomicAdd(&P[(size_t)s * MDIM + m0 + mL], acc2[i2][j2][reg]);
      }
}

// ---------------------------------------------------------------------------
// 6) normalize P in place -> sim (+ mask, positive_map)
// grid (256), 256 thr
__global__ void k_reduce(float* __restrict__ P, const float* __restrict__ vn2,
                         const float* __restrict__ snorm2,
                         const int* __restrict__ mask, float* __restrict__ pm) {
  __shared__ float invSn[64];
  const int tid = threadIdx.x;
  if (tid < 64) invSn[tid] = 1.f / fmaxf(sqrtf(snorm2[tid]), 1e-8f);
  __syncthreads();
  const int m = blockIdx.x * 256 + tid;
  const float invVn = 1.f / fmaxf(sqrtf(vn2[m]), 1e-8f);
  const int mk = mask[m];
  const int b0 = m >> 10;
#pragma unroll 8
  for (int s = 0; s < 64; s++) {
    float val = P[(size_t)s * MDIM + m] * invVn * invSn[s];
    if (mk == 0) val = -__builtin_inff();
    P[(size_t)s * MDIM + m] = val;           // in place: P becomes sim
    if (s == b0) pm[m] = val;
  }
}

// ---------------------------------------------------------------------------
// 7) per-(s,b): top-50, IoU penalty, score — ONE WAVE per (s,b)
// grid (1024), 256 thr (4 waves)
__global__ void k_topk(const float* __restrict__ sim, const float* __restrict__ iou,
                       const float* __restrict__ lam, float* __restrict__ scores) {
  const int wave = threadIdx.x >> 6, lane = threadIdx.x & 63;
  const int sb = blockIdx.x * 4 + wave;
  const int s = sb >> 6, b = sb & 63;
  __shared__ float tvs[4][VNUM];
  __shared__ int tis[4][VNUM];

  const float* row = sim + (size_t)s * MDIM + (size_t)b * 1024;
  float v[16];
#pragma unroll
  for (int j = 0; j < 16; j++) v[j] = row[j * 64 + lane];

  for (int k = 0; k < VNUM; k++) {
    float bv = v[0]; int bj = 0;
#pragma unroll
    for (int j = 1; j < 16; j++)
      if (v[j] > bv) { bv = v[j]; bj = j; }
    int bidx = bj * 64 + lane;
#pragma unroll
    for (int o = 1; o < 64; o <<= 1) {
      const float ov = __shfl_xor(bv, o);
      const int oi = __shfl_xor(bidx, o);
      if (ov > bv || (ov == bv && oi < bidx)) { bv = ov; bidx = oi; }
    }
    if (lane == 0) { tvs[wave][k] = bv; tis[wave][k] = bidx; }
    const int wj = bidx >> 6;
    const bool mine = (bidx & 63) == lane;
#pragma unroll
    for (int j = 0; j < 16; j++)
      if (mine && wj == j) v[j] = -__builtin_inff();
  }
  __syncthreads();

  float contrib = 0.f;
  if (lane < VNUM) {
    const int myidx = tis[wave][lane];
    float pen = 0.f;
    for (int l = lane + 1; l < VNUM; l++) {
      const float u = iou[(size_t)tis[wave][l] * 1024 + myidx];
      pen += u * u;
    }
    contrib = tvs[wave][lane] * expf(-pen / lam[0]);
  }
#pragma unroll
  for (int o = 32; o; o >>= 1) contrib += __shfl_down(contrib, o);
  if (lane == 0) scores[s * 64 + b] = contrib * (1.f / VNUM);
}

// ---------------------------------------------------------------------------
// 8) final 64x64 loss reduction
__global__ void k_loss(const float* __restrict__ scores, float* __restrict__ out) {
  __shared__ float S[64 * 64];
  __shared__ float diag[64];
  __shared__ float rmax[64], cmax[64];
  const int tid = threadIdx.x;
#pragma unroll
  for (int q = 0; q < 16; q++) S[tid + q * 256] = scores[tid + q * 256];
  __syncthreads();
  if (tid < 64) diag[tid] = S[tid * 64 + tid];
  __syncthreads();
  if (tid < 64) {
    float rm = 0.f, cm = 0.f;
    for (int x = 0; x < 64; x++) {
      if (x != tid) {
        const float cs = 0.2f + S[tid * 64 + x] - diag[tid];
        rm = fmaxf(rm, fmaxf(cs, 0.f));
        const float ci = 0.2f + S[x * 64 + tid] - diag[tid];
        cm = fmaxf(cm, fmaxf(ci, 0.f));
      }
    }
    rmax[tid] = rm; cmax[tid] = cm;
  }
  __syncthreads();
  if (tid == 0) {
    float L = 0.f;
    for (int t = 0; t < 64; t++) L += rmax[t] + cmax[t];
    out[0] = L * (1.f / 64.f);
  }
}

// ---------------------------------------------------------------------------
extern "C" void kernel_launch(void* const* d_in, const int* in_sizes, int n_in,
                              void* d_out, int out_size, void* d_ws, size_t ws_size,
                              hipStream_t stream) {
  (void)in_sizes; (void)n_in; (void)out_size; (void)ws_size;
  const float* videos = (const float*)d_in[0];
  const float* sent   = (const float*)d_in[1];
  const float* lam    = (const float*)d_in[2];
  const int*   mask   = (const int*)d_in[3];
  const float* iou    = (const float*)d_in[4];
  const float* W_v    = (const float*)d_in[6];
  const float* b_v    = (const float*)d_in[7];
  const float* W_s    = (const float*)d_in[8];
  const float* b_s    = (const float*)d_in[9];
  float* out = (float*)d_out;

  char* ws = (char*)d_ws;
  unsigned short* At   = (unsigned short*)(ws + 0);           // 128 MB
  float* sim           = (float*)(ws + 134217728);            // 16 MB (= P)
  float* vpart         = (float*)(ws + 134217728);            // 4 MB, aliases P
                                                              // (consumed before P memset)
  unsigned short* Wt   = (unsigned short*)(ws + 150994944);   // 2 MB
  unsigned short* scat = (unsigned short*)(ws + 153092096);   // 128 KB
  float* vsums         = (float*)(ws + 153223168);            // 256 KB
  float* snorm2        = (float*)(ws + 153485312);            // 256 B
  float* csW           = (float*)(ws + 153485568);            // 4 KB
  float* scores        = (float*)(ws + 153489664);            // 16 KB
  float* vn2           = (float*)(ws + 153509888);            // 256 KB

  hipMemsetAsync(snorm2, 0, 256, stream);
  hipMemsetAsync(vn2, 0, 262144, stream);

  k_transpose_videos<<<dim3(16, 16, 64), 256, 0, stream>>>(videos, At, vpart);
  k_vsum_reduce<<<256, 256, 0, stream>>>(vpart, vsums);
  // vpart consumed -> now safe to zero P (same bytes)
  hipMemsetAsync(sim, 0, 16777216, stream);
  k_transpose_W<<<dim3(8, 32, 4), 256, 0, stream>>>(W_v, Wt);
  k_row_sums<<<256, 256, 0, stream>>>(Wt, csW, 1024);
  k_scat<<<dim3(64, 4), 1024, 0, stream>>>(sent, W_s, b_s, scat, snorm2);
  k_gemm_part<<<dim3(2048), 256, 0, stream>>>(At, Wt, vsums, csW, b_v, scat,
                                              sim /*P*/, vn2);
  k_reduce<<<256, 256, 0, stream>>>(sim /*P->sim*/, vn2, snorm2, mask, out + 1);
  k_topk<<<dim3(1024), 256, 0, stream>>>(sim, iou, lam, scores);
  k_loss<<<1, 256, 0, stream>>>(scores, out);
}